// Round 15
// baseline (124.380 us; speedup 1.0000x reference)
//
#include <hip/hip_runtime.h>
#include <hip/hip_bf16.h>

// ---------------- problem constants ----------------
#define Bc   8
#define Cc   256
#define Hc   64
#define Wc   64
#define HWc  4096
#define KDIM 1024          // M*C

#define LOSS_IDX   8388608
#define OFFS_BASE  8388609        // offsets output base in d_out

// ---------------- ws layout (bytes) ----------------
#define XT_OFF     0u              // bf16 [B][HW][512] hi    33,554,432
#define HEAD_OFF   33554432u       // Xlo8 u8 [B][HW][512] (conv) THEN head fp8 (tail, 32MB)
#define XF8_OFF    67108864u       // fp8 [B][HW][256] F_c     8,388,608
#define WC8_OFF    75497472u       // fp8 W blob [8 steps][9216 B] = 73,728
#define WBF_OFF    100663296u      // fp8 [C][KDIM]            262,144
#define ATTN_OFF   101187584u      // f32 [B][M][HW]           524,288
#define ALPHA_OFF  101711872u      // f32 [8]
#define LOSSP_OFF  101712128u      // f32 [256]
#define WREP_OFF   101714176u      // bf16 wconv blob          221,184 (8 x 1728 granules x 16B)
#define ZPAGE_OFF  101935360u      // 256 B zeros

typedef unsigned short u16;
typedef unsigned char u8;
typedef __attribute__((ext_vector_type(8))) short bf16x8;
typedef __attribute__((ext_vector_type(8))) unsigned short u16x8;
typedef __attribute__((ext_vector_type(4))) float f32x4;
typedef __attribute__((ext_vector_type(2))) float f32x2;

#define GLL(gsrc, ldst) __builtin_amdgcn_global_load_lds( \
    (const __attribute__((address_space(1))) unsigned int*)(gsrc), \
    (__attribute__((address_space(3))) unsigned int*)(ldst), 16, 0, 0)

static __device__ __forceinline__ u16 f2bf(float f) {
    unsigned int u = __float_as_uint(f);
    unsigned int r = (u + 0x7FFFu + ((u >> 16) & 1u)) >> 16;
    return (u16)r;
}
static __device__ __forceinline__ float bf2f(u16 h) {
    return __uint_as_float(((unsigned int)h) << 16);
}
static __device__ __forceinline__ unsigned int pk4_fp8(float a, float b, float c, float d) {
    int r = __builtin_amdgcn_cvt_pk_fp8_f32(a, b, 0, false);
    r = __builtin_amdgcn_cvt_pk_fp8_f32(c, d, r, true);
    return (unsigned int)r;
}

// ---------------- kernel 1: pack X v5 — register transpose, full-cache-line writes ----------------
// blocks 0..2047: pack (b 8) x (chtile 4 x 128ch) x (postile 64 x 64pos).
// blocks 2048..2303: wfuse fp8; 2304..2311: wconv blobs; 2312: zpage
__global__ __launch_bounds__(256) void pack_x(
    const float* __restrict__ Fx, const float* __restrict__ Fc,
    u16* __restrict__ Xt, u8* __restrict__ Xlo8, u8* __restrict__ Xf8,
    const float* __restrict__ wf, u8* __restrict__ wf8,
    const float* __restrict__ w_off, const float* __restrict__ w_attn,
    u16* __restrict__ wconv, u8* __restrict__ wconv8, float* __restrict__ zpage) {
    const int tid = threadIdx.x;
    if (blockIdx.x < 2048) {
        const int blk = blockIdx.x;
        const int b = blk >> 8;
        const int rem = blk & 255;
        const int ch0 = (rem >> 6) << 7;           // 0,128,256,384
        const int pos0 = (rem & 63) << 6;          // 64-position tile
        const int cs = (tid & 15) << 3;            // 8-ch sub-block: 0..120
        const int p4 = (tid >> 4) << 2;            // 0..60
        const float* basep = (ch0 < 256)
            ? Fx + (((size_t)b << 8) + ch0) * HWc
            : Fc + (((size_t)b << 8) + (ch0 - 256)) * HWc;
        float4 v[8];
#pragma unroll
        for (int k = 0; k < 8; ++k)
            v[k] = *(const float4*)(basep + (size_t)(cs + k) * HWc + pos0 + p4);
#pragma unroll
        for (int j = 0; j < 4; ++j) {
            float w[8];
#pragma unroll
            for (int k = 0; k < 8; ++k) w[k] = ((const float*)&v[k])[j];
            u16x8 hi8;
#pragma unroll
            for (int k = 0; k < 8; ++k) hi8[k] = f2bf(w[k]);
            const size_t row = ((size_t)b << 12) + pos0 + p4 + j;
            *(u16x8*)(Xt + row * 512 + ch0 + cs) = hi8;
            uint2 lo8;
            lo8.x = pk4_fp8((w[0] - bf2f(hi8[0])) * 256.f, (w[1] - bf2f(hi8[1])) * 256.f,
                            (w[2] - bf2f(hi8[2])) * 256.f, (w[3] - bf2f(hi8[3])) * 256.f);
            lo8.y = pk4_fp8((w[4] - bf2f(hi8[4])) * 256.f, (w[5] - bf2f(hi8[5])) * 256.f,
                            (w[6] - bf2f(hi8[6])) * 256.f, (w[7] - bf2f(hi8[7])) * 256.f);
            *(uint2*)(Xlo8 + row * 512 + ch0 + cs) = lo8;
            if (ch0 >= 256) {
                uint2 f8;
                f8.x = pk4_fp8(w[0], w[1], w[2], w[3]);
                f8.y = pk4_fp8(w[4], w[5], w[6], w[7]);
                *(uint2*)(Xf8 + row * 256 + (ch0 - 256) + cs) = f8;
            }
        }
    } else if (blockIdx.x < 2304) {
        const int i = (blockIdx.x - 2048) * 256 + tid;
        const float4 v = *(const float4*)(wf + (size_t)i * 4);
        *(unsigned int*)(wf8 + (size_t)i * 4) = pk4_fp8(v.x, v.y, v.z, v.w);
    } else if (blockIdx.x < 2312) {
        const int step = blockIdx.x - 2304;
        for (int n = tid; n < 1728; n += 256) {   // bf16 blob (hi+lo planes)
            const int par = n & 1;
            const int slot = (n >> 1) & 3;
            const int pair = (n >> 3) % 6;
            const int tap = (n / 48) % 9;
            const int prec = (n / 432) & 1;
            const int sub = n / 864;
            const int oc = pair * 2 + par;
            const int c = slot ^ (pair & 3);
            const int ch = step * 64 + sub * 32 + c * 8;
            u16x8 out;
#pragma unroll
            for (int j = 0; j < 8; ++j) {
                const float v = (oc < 8)
                    ? w_off[((size_t)oc * 512 + ch + j) * 9 + tap]
                    : w_attn[((size_t)(oc - 8) * 512 + ch + j) * 9 + tap];
                const u16 h = f2bf(v);
                out[j] = prec ? f2bf(v - bf2f(h)) : h;
            }
            *(u16x8*)(wconv + ((size_t)step * 1728 + n) * 8) = out;
        }
        for (int n = tid; n < 1152; n += 256) {   // fp8 W-hi blob [sub2][tap9][oc16][slot4]
            const int slot = n & 3;
            const int oc = (n >> 2) & 15;
            const int tap = (n >> 6) % 9;
            const int sub = n / 576;
            const int g = slot ^ (oc >> 2);
            const int ch = step * 64 + sub * 32 + g * 8;
            float v[8];
#pragma unroll
            for (int j = 0; j < 8; ++j)
                v[j] = (oc < 8) ? w_off[((size_t)oc * 512 + ch + j) * 9 + tap]
                     : (oc < 12) ? w_attn[((size_t)(oc - 8) * 512 + ch + j) * 9 + tap] : 0.f;
            uint2 o;
            o.x = pk4_fp8(v[0], v[1], v[2], v[3]);
            o.y = pk4_fp8(v[4], v[5], v[6], v[7]);
            *(uint2*)(wconv8 + (size_t)step * 9216 + n * 8) = o;
        }
    } else {
        if (tid < 64) zpage[tid] = 0.f;
    }
}

// ---------------- kernel 2: conv as split MFMA implicit GEMM (hi bf16, lo fp8) ----------------
// LDS: X-hi [buf2][row4][pos66][chunk8]x16B (row 8448, buf 33792)            0..67584
//      X-lo8 [buf2][row4][pos66][chunk4]x16B (row 4224, buf 16896)       67584..101376
//      B bf16 [sub2][prec2][tap9][pair6][slot4][par2]x16B              101376..129024
//      B fp8  [sub2][tap9][oc16][slot4]x8B                             129024..138240
__global__ __launch_bounds__(512) void conv_mfma(
    const u16* __restrict__ Xt, const u8* __restrict__ Xlo8,
    const u16* __restrict__ wconv, const u8* __restrict__ wconv8,
    const float* __restrict__ zpage,
    const float* __restrict__ b_off, const float* __restrict__ b_attn,
    float* __restrict__ dout, float* __restrict__ attnb, float* __restrict__ lossp) {
    __shared__ char smem[138240];

    const int tid = threadIdx.x;
    const int wv = tid >> 6, lane = tid & 63;
    const int gp = wv >> 2, qd = wv & 3;
    const int l15 = lane & 15, g = lane >> 4;
    const int b = blockIdx.x >> 5;
    const int h0 = (blockIdx.x & 31) * 2;
    const int wrow = qd >> 1, wcol0 = (qd & 1) * 32;

    // zero halo granules (pos 0 and 65)
    if (tid < 192) {
        const float4 z = {0.f, 0.f, 0.f, 0.f};
        if (tid < 128) {
            const int bu = tid >> 6, rr = (tid >> 4) & 3, hp = (tid >> 3) & 1, cc = tid & 7;
            *(float4*)(smem + bu * 33792 + rr * 8448 + (hp ? 65 : 0) * 128 + cc * 16) = z;
        } else {
            const int t2 = tid - 128;
            const int bu = t2 >> 5, rr = (t2 >> 3) & 3, hp = (t2 >> 2) & 1, cc = t2 & 3;
            *(float4*)(smem + 67584 + bu * 16896 + rr * 4224 + (hp ? 65 : 0) * 64 + cc * 16) = z;
        }
    }

    int pre[2][3], plo[2][3];
#pragma unroll
    for (int f = 0; f < 2; ++f)
#pragma unroll
        for (int dx = 0; dx < 3; ++dx) {
            const int p = wcol0 + f * 16 + l15 + dx;      // 0..65
            pre[f][dx] = wrow * 8448 + p * 128 + ((((gp << 2) | g) ^ (p & 7)) << 4);
            const int cl = (gp * 2 + (g >> 1)) ^ ((p & 3) ^ ((p >> 2) & 3));
            plo[f][dx] = 67584 + wrow * 4224 + p * 64 + cl * 16 + (g & 1) * 8;
        }
    const int bpair = l15 >> 1, bpar = l15 & 1;
    const int vb = 101376 + gp * 13824 + bpair * 128 + ((g ^ (bpair & 3)) << 5) + bpar * 16;
    const int vb8 = 129024 + gp * 4608 + l15 * 32 + ((g ^ (l15 >> 2)) << 3);

    auto stage_X = [&](int step, int buf) {
#pragma unroll
        for (int k = 0; k < 7; ++k) {
            const int f = wv * 7 + k;                     // 0..55
            if (f < 36) {                                 // hi plane (bf16)
                const int rr = f / 9, i = f % 9;
                const int p = i * 8 + (lane >> 3);
                const int c = (lane & 7) ^ (p & 7);
                const int h = h0 - 1 + rr;
                const bool act = (p >= 1) && (p <= 64);
                const char* gsrc = (h >= 0 && h < 64)
                    ? (const char*)(Xt + (((size_t)((b << 12) + h * 64 + p - 1)) << 9) + step * 64 + c * 8)
                    : (const char*)zpage + ((lane & 7) << 4);
                char* ldst = smem + buf * 33792 + rr * 8448 + i * 1024;
                if (act) GLL(gsrc, ldst);
            } else {                                      // lo plane (fp8)
                const int f2 = f - 36;
                const int rr = f2 / 5, i = f2 % 5;
                const int p = i * 16 + (lane >> 2);
                const int c = (lane & 3) ^ ((p & 3) ^ ((p >> 2) & 3));
                const int h = h0 - 1 + rr;
                const bool act = (p >= 1) && (p <= 64);
                const char* gsrc = (h >= 0 && h < 64)
                    ? (const char*)(Xlo8 + (((size_t)((b << 12) + h * 64 + p - 1)) << 9) + step * 64 + c * 16)
                    : (const char*)zpage + ((lane & 3) << 4);
                char* ldst = smem + 67584 + buf * 16896 + rr * 4224 + i * 1024;
                if (act) GLL(gsrc, ldst);
            }
        }
    };
    auto stage_B = [&](int step) {
        for (int i = wv; i < 36; i += 8) {
            if (i < 27) {
                const char* gsrc = (const char*)wconv + (((size_t)step * 1728) + i * 64 + lane) * 16;
                GLL(gsrc, smem + 101376 + i * 1024);
            } else {
                const int j = i - 27;
                const char* gsrc = (const char*)wconv8 + (size_t)step * 9216 + j * 1024 + lane * 16;
                GLL(gsrc, smem + 129024 + j * 1024);
            }
        }
    };

    __syncthreads();                 // halo zeros visible
    stage_X(0, 0);
    stage_B(0);
    __syncthreads();                 // full drain

    f32x4 acc0 = {}, acc1 = {}, al0 = {}, al1 = {};

    for (int step = 0; step < 8; ++step) {
        if (step < 7) {
            stage_X(step + 1, (step + 1) & 1);
            asm volatile("s_waitcnt vmcnt(7)" ::: "memory");
        } else {
            asm volatile("s_waitcnt vmcnt(0)" ::: "memory");
        }
        __builtin_amdgcn_s_barrier();
        __builtin_amdgcn_sched_barrier(0);

#pragma unroll
        for (int tap = 0; tap < 9; ++tap) {
            const int dy = tap / 3, dx = tap % 3;
            const bf16x8 bh = *(const bf16x8*)(smem + vb + tap * 768);
            const bf16x8 bl = *(const bf16x8*)(smem + vb + 6912 + tap * 768);
            const long b8 = *(const long*)(smem + vb8 + tap * 512);
            const bf16x8 a0h = *(const bf16x8*)(smem + pre[0][dx] + dy * 8448);
            const bf16x8 a1h = *(const bf16x8*)(smem + pre[1][dx] + dy * 8448);
            const long a0l = *(const long*)(smem + plo[0][dx] + dy * 4224);
            const long a1l = *(const long*)(smem + plo[1][dx] + dy * 4224);
            acc0 = __builtin_amdgcn_mfma_f32_16x16x32_bf16(a0h, bh, acc0, 0, 0, 0);
            acc1 = __builtin_amdgcn_mfma_f32_16x16x32_bf16(a1h, bh, acc1, 0, 0, 0);
            acc0 = __builtin_amdgcn_mfma_f32_16x16x32_bf16(a0h, bl, acc0, 0, 0, 0);
            acc1 = __builtin_amdgcn_mfma_f32_16x16x32_bf16(a1h, bl, acc1, 0, 0, 0);
            al0 = __builtin_amdgcn_mfma_f32_16x16x32_fp8_fp8(a0l, b8, al0, 0, 0, 0);
            al1 = __builtin_amdgcn_mfma_f32_16x16x32_fp8_fp8(a1l, b8, al1, 0, 0, 0);
        }

        __builtin_amdgcn_sched_barrier(0);
        __builtin_amdgcn_s_barrier();
        __builtin_amdgcn_sched_barrier(0);
        if (step < 7) stage_B(step + 1);
        const int dh = (step & 1) ? -33792 : 33792;
        const int dl = (step & 1) ? -16896 : 16896;
#pragma unroll
        for (int f = 0; f < 2; ++f)
#pragma unroll
            for (int dx = 0; dx < 3; ++dx) { pre[f][dx] += dh; plo[f][dx] += dl; }
    }

    // ---- epilogue ----
    __syncthreads();
    float* eL = (float*)smem;        // [2 groups][12 oc][128 pix]
    if (l15 < 12) {
#pragma unroll
        for (int r = 0; r < 4; ++r) {
            const int px0 = wrow * 64 + wcol0 + g * 4 + r;
            eL[(gp * 12 + l15) * 128 + px0] = acc0[r] + al0[r] * (1.f / 256.f);
            eL[(gp * 12 + l15) * 128 + px0 + 16] = acc1[r] + al1[r] * (1.f / 256.f);
        }
    }
    __syncthreads();
    float labs = 0.f;
    if (tid < 256) {
        const int oc = tid >> 5, seg = tid & 31;
        const float4 v0 = *(const float4*)&eL[oc * 128 + seg * 4];
        const float4 v1 = *(const float4*)&eL[(12 + oc) * 128 + seg * 4];
        const float bo = b_off[oc];
        float4 o;
        o.x = v0.x + v1.x + bo; o.y = v0.y + v1.y + bo;
        o.z = v0.z + v1.z + bo; o.w = v0.w + v1.w + bo;
        *(float4*)(dout + OFFS_BASE + (((size_t)b * 8 + oc) << 12) + h0 * 64 + seg * 4) = o;
        labs = fabsf(o.x) + fabsf(o.y) + fabsf(o.z) + fabsf(o.w);
    } else if (tid < 384) {
        const int t2 = tid - 256;
        const int oc = t2 >> 5, seg = t2 & 31;
        const float4 v0 = *(const float4*)&eL[(8 + oc) * 128 + seg * 4];
        const float4 v1 = *(const float4*)&eL[(20 + oc) * 128 + seg * 4];
        const float ba = b_attn[oc];
        float4 o;
        o.x = 1.f / (1.f + expf(-(v0.x + v1.x + ba)));
        o.y = 1.f / (1.f + expf(-(v0.y + v1.y + ba)));
        o.z = 1.f / (1.f + expf(-(v0.z + v1.z + ba)));
        o.w = 1.f / (1.f + expf(-(v0.w + v1.w + ba)));
        *(float4*)(attnb + (((size_t)b * 4 + oc) << 12) + h0 * 64 + seg * 4) = o;
    }
#pragma unroll
    for (int off = 32; off; off >>= 1) labs += __shfl_down(labs, off);
    float* wr = (float*)(smem + 14336);
    if (lane == 0) wr[wv] = labs;
    __syncthreads();
    if (tid == 0) {
        float s = 0.f;
#pragma unroll
        for (int i = 0; i < 8; ++i) s += wr[i];
        lossp[blockIdx.x] = s;
    }
}

// ---------------- kernel 3: loss reduce + alpha MLP ----------------
__global__ __launch_bounds__(256) void finalize_small(
    const float* __restrict__ lossp, const float* __restrict__ t,
    const float* __restrict__ w1, const float* __restrict__ b1,
    const float* __restrict__ w2, const float* __restrict__ b2,
    float* __restrict__ dout, float* __restrict__ alpha) {
    __shared__ float sd[4];
    const int tid = threadIdx.x;
    float s = lossp[tid];
#pragma unroll
    for (int off = 32; off; off >>= 1) s += __shfl_down(s, off);
    if ((tid & 63) == 0) sd[tid >> 6] = s;
    __syncthreads();
    if (tid == 0) dout[LOSS_IDX] = (sd[0] + sd[1] + sd[2] + sd[3]) * (1.f / 262144.f);

    for (int b = 0; b < 8; ++b) {
        __syncthreads();
        float v = 0.f;
        if (tid < 128) v = fmaxf(fmaf(t[b], w1[tid], b1[tid]), 0.f) * w2[tid];
#pragma unroll
        for (int off = 32; off; off >>= 1) v += __shfl_down(v, off);
        if ((tid & 63) == 0) sd[tid >> 6] = v;
        __syncthreads();
        if (tid == 0) alpha[b] = 1.f / (1.f + expf(-(sd[0] + sd[1] + b2[0])));
    }
}

// ---------------- kernel 4: bilinear gather (fp8) -> head (fp8) ----------------
__global__ __launch_bounds__(256) void sample_head(
    const u8* __restrict__ Xf8, const float* __restrict__ dout,
    const float* __restrict__ attnb, const float* __restrict__ Wp,
    u8* __restrict__ head) {
    const int tid = threadIdx.x;
    const int wv = tid >> 6, lane = tid & 63;
    const int item = blockIdx.x * 4 + wv;           // (b, m, p)
    const int b = item >> 14;
    const int m = (item >> 12) & 3;
    const int p = item & 4095;
    const int h = p >> 6, wc = p & 63;
    const int hl = lane >> 5, l32 = lane & 31;

    const float off0 = dout[OFFS_BASE + (((size_t)b * 8 + 2 * m) << 12) + p];
    const float off1 = dout[OFFS_BASE + (((size_t)b * 8 + 2 * m + 1) << 12) + p];
    const float a    = attnb[(((size_t)b * 4 + m) << 12) + p];

    const float ysh = -1.f + h * (2.f / 63.f);
    const float xsw = -1.f + wc * (2.f / 63.f);

    const u8* base = Xf8 + (((size_t)b << 12) << 8) + l32 * 8;
    float acc[8] = {};

#pragma unroll
    for (int r = 0; r < 4; ++r) {
        const float bpy = (r < 2) ? -0.5f : 0.5f;
        const float bpx = (r & 1) ? 0.5f : -0.5f;
        const float c0 = ysh + bpy + off0;   // used as gx (reference quirk)
        const float c1 = xsw + bpx + off1;   // used as gy
        const float ix = (c0 + 1.f) * 31.5f;
        const float iy = (c1 + 1.f) * 31.5f;
        const float x0 = floorf(ix), y0 = floorf(iy);
        const float wx1 = ix - x0, wx0 = 1.f - wx1;
        const float wy1 = iy - y0, wy0 = 1.f - wy1;
        const float xf = x0 + hl;
        const float wxl = (hl ? wx1 : wx0) * (Wp[m * 4 + r] * a);
        const bool xin = (xf >= 0.f) && (xf < 64.f);
        const bool v0 = xin && (y0 >= 0.f) && (y0 < 64.f);
        const bool v1 = xin && (y0 >= -1.f) && (y0 < 63.f);
        const int xi = (int)xf;
        uint2 u0, u1;
        if (v0) u0 = *(const uint2*)(base + ((size_t)((((int)y0) << 6) + xi)) * 256);
        if (v1) u1 = *(const uint2*)(base + ((size_t)((((int)y0 + 1) << 6) + xi)) * 256);
        if (v0) {
            const float w = wxl * wy0;
            const f32x2 pa = __builtin_amdgcn_cvt_pk_f32_fp8((int)u0.x, false);
            const f32x2 pb = __builtin_amdgcn_cvt_pk_f32_fp8((int)u0.x, true);
            const f32x2 pc = __builtin_amdgcn_cvt_pk_f32_fp8((int)u0.y, false);
            const f32x2 pd = __builtin_amdgcn_cvt_pk_f32_fp8((int)u0.y, true);
            acc[0] = fmaf(w, pa[0], acc[0]); acc[1] = fmaf(w, pa[1], acc[1]);
            acc[2] = fmaf(w, pb[0], acc[2]); acc[3] = fmaf(w, pb[1], acc[3]);
            acc[4] = fmaf(w, pc[0], acc[4]); acc[5] = fmaf(w, pc[1], acc[5]);
            acc[6] = fmaf(w, pd[0], acc[6]); acc[7] = fmaf(w, pd[1], acc[7]);
        }
        if (v1) {
            const float w = wxl * wy1;
            const f32x2 pa = __builtin_amdgcn_cvt_pk_f32_fp8((int)u1.x, false);
            const f32x2 pb = __builtin_amdgcn_cvt_pk_f32_fp8((int)u1.x, true);
            const f32x2 pc = __builtin_amdgcn_cvt_pk_f32_fp8((int)u1.y, false);
            const f32x2 pd = __builtin_amdgcn_cvt_pk_f32_fp8((int)u1.y, true);
            acc[0] = fmaf(w, pa[0], acc[0]); acc[1] = fmaf(w, pa[1], acc[1]);
            acc[2] = fmaf(w, pb[0], acc[2]); acc[3] = fmaf(w, pb[1], acc[3]);
            acc[4] = fmaf(w, pc[0], acc[4]); acc[5] = fmaf(w, pc[1], acc[5]);
            acc[6] = fmaf(w, pd[0], acc[6]); acc[7] = fmaf(w, pd[1], acc[7]);
        }
    }
#pragma unroll
    for (int j = 0; j < 8; ++j) acc[j] += __shfl_xor(acc[j], 32);
    if (lane < 32) {
        uint2 o;
        o.x = pk4_fp8(acc[0], acc[1], acc[2], acc[3]);
        o.y = pk4_fp8(acc[4], acc[5], acc[6], acc[7]);
        *(uint2*)(head + ((((size_t)b << 12) + p)) * KDIM + m * 256 + l32 * 8) = o;
    }
}

// ---------------- kernel 5: fuse GEMM (fp8 MFMA, K-tile 64, swizzled global_load_lds) ----------------
__global__ __launch_bounds__(256) void fuse_gemm(
    const u8* __restrict__ head, const u8* __restrict__ wf8,
    const float* __restrict__ Fx, const float* __restrict__ bfuse,
    const float* __restrict__ alpha, float* __restrict__ dout) {
    __shared__ __attribute__((aligned(16))) char smem[2][2][8192];   // [buf][A/B][128*64]

    const int tid = threadIdx.x;
    const int lane = tid & 63, wv = tid >> 6;
    const int wm = wv >> 1, wn = wv & 1;
    const int l15 = lane & 15, g = lane >> 4;
    const size_t arow0 = (size_t)blockIdx.x * 128;
    const int co0 = blockIdx.y * 128;

    f32x4 acc[4][4] = {};

    const int isB = wv >> 1;
    const int whalf = wv & 1;
    const u8* srcbase = isB ? wf8 + (size_t)co0 * KDIM : head + arow0 * KDIM;

    auto stage = [&](int kt, int buf) {
#pragma unroll
        for (int i = 0; i < 4; ++i) {
            const int row = whalf * 64 + i * 16 + (lane >> 2);
            const int gq = (lane & 3) ^ ((row >> 1) & 3);
            const u8* gsrc = srcbase + (size_t)row * KDIM + kt * 64 + gq * 16;
            char* ldst = smem[buf][isB] + (whalf * 64 + i * 16) * 64;
            GLL(gsrc, ldst);
        }
    };

    stage(0, 0);
    __syncthreads();

    for (int kt = 0; kt < 16; ++kt) {
        if (kt < 15) {
            stage(kt + 1, (kt + 1) & 1);
            asm volatile("s_waitcnt vmcnt(4)" ::: "memory");
        } else {
            asm volatile("s_waitcnt vmcnt(0)" ::: "memory");
        }
        __builtin_amdgcn_s_barrier();
        __builtin_amdgcn_sched_barrier(0);

        const char* Ab = smem[kt & 1][0];
        const char* Bb = smem[kt & 1][1];
#pragma unroll
        for (int s = 0; s < 2; ++s) {
            const int gg = s * 4 + g;
            long av[4], bv[4];
#pragma unroll
            for (int f = 0; f < 4; ++f) {
                const int ra = wm * 64 + f * 16 + l15;
                const int rb = wn * 64 + f * 16 + l15;
                const int sa = (gg >> 1) ^ ((ra >> 1) & 3);
                const int sb = (gg >> 1) ^ ((rb >> 1) & 3);
                av[f] = *(const long*)(Ab + ra * 64 + sa * 16 + (gg & 1) * 8);
                bv[f] = *(const long*)(Bb + rb * 64 + sb * 16 + (gg & 1) * 8);
            }
#pragma unroll
            for (int i = 0; i < 4; ++i)
#pragma unroll
                for (int j = 0; j < 4; ++j)
                    acc[i][j] = __builtin_amdgcn_mfma_f32_16x16x32_fp8_fp8(av[i], bv[j], acc[i][j], 0, 0, 0);
        }

        __builtin_amdgcn_sched_barrier(0);
        __builtin_amdgcn_s_barrier();
        __builtin_amdgcn_sched_barrier(0);
    }

    const int b = (int)(arow0 >> 12);
    const float al = alpha[b], il = 1.f - al;
    const int pixbase = (int)(arow0 & 4095);
#pragma unroll
    for (int i = 0; i < 4; ++i) {
        const int rowl = wm * 64 + i * 16 + g * 4;
        const int pix = pixbase + rowl;
#pragma unroll
        for (int j = 0; j < 4; ++j) {
            const int co = co0 + wn * 64 + j * 16 + l15;
            const float bias = bfuse[co];
            const size_t idx = (((size_t)b << 8) + co) * HWc + pix;
            const float4 fx = *(const float4*)(Fx + idx);
            const f32x4 v = acc[i][j];
            float4 o;
            o.x = al * (v[0] + bias) + il * fx.x;
            o.y = al * (v[1] + bias) + il * fx.y;
            o.z = al * (v[2] + bias) + il * fx.z;
            o.w = al * (v[3] + bias) + il * fx.w;
            *(float4*)(dout + idx) = o;
        }
    }
}

// ---------------- launcher ----------------
extern "C" void kernel_launch(void* const* d_in, const int* in_sizes, int n_in,
                              void* d_out, int out_size, void* d_ws, size_t ws_size,
                              hipStream_t stream) {
    const float* F_x    = (const float*)d_in[0];
    const float* F_c    = (const float*)d_in[1];
    const float* t      = (const float*)d_in[2];
    const float* w_off  = (const float*)d_in[3];
    const float* b_off  = (const float*)d_in[4];
    const float* w_attn = (const float*)d_in[5];
    const float* b_attn = (const float*)d_in[6];
    const float* Wp     = (const float*)d_in[7];
    const float* w_fuse = (const float*)d_in[8];
    const float* b_fuse = (const float*)d_in[9];
    const float* w1     = (const float*)d_in[10];
    const float* b1     = (const float*)d_in[11];
    const float* w2     = (const float*)d_in[12];
    const float* b2     = (const float*)d_in[13];
    float* out = (float*)d_out;

    char* ws = (char*)d_ws;
    u16*   Xt     = (u16*)(ws + XT_OFF);
    u8*    Xlo8   = (u8*)(ws + HEAD_OFF);     // conv-only; dead before head write
    u8*    head8  = (u8*)(ws + HEAD_OFF);     // fp8 head, 32 MB
    u8*    Xf8    = (u8*)(ws + XF8_OFF);
    u8*    wconv8 = (u8*)(ws + WC8_OFF);
    u8*    wf8    = (u8*)(ws + WBF_OFF);
    float* attnb  = (float*)(ws + ATTN_OFF);
    float* alphb  = (float*)(ws + ALPHA_OFF);
    float* lossp  = (float*)(ws + LOSSP_OFF);
    u16*   wconv  = (u16*)(ws + WREP_OFF);
    float* zpage  = (float*)(ws + ZPAGE_OFF);

    pack_x<<<dim3(2313), dim3(256), 0, stream>>>(F_x, F_c, Xt, Xlo8, Xf8,
                                                 w_fuse, wf8, w_off, w_attn,
                                                 wconv, wconv8, zpage);
    conv_mfma<<<dim3(256), dim3(512), 0, stream>>>(Xt, Xlo8, wconv, wconv8, zpage,
                                                   b_off, b_attn, out, attnb, lossp);
    finalize_small<<<dim3(1), dim3(256), 0, stream>>>(lossp, t, w1, b1, w2, b2, out, alphb);
    sample_head<<<dim3(32768), dim3(256), 0, stream>>>(Xf8, out, attnb, Wp, head8);
    fuse_gemm<<<dim3(256, 2), dim3(256), 0, stream>>>(head8, wf8, F_x, b_fuse, alphb, out);
}

// Round 16
// 104.557 us; speedup vs baseline: 1.1896x; 1.1896x over previous
//
#include <hip/hip_runtime.h>
#include <hip/hip_bf16.h>
#include <hip/hip_fp16.h>

// ---------------- problem constants ----------------
#define Bc   8
#define Cc   256
#define Hc   64
#define Wc   64
#define HWc  4096
#define KDIM 1024          // M*C

#define LOSS_IDX   8388608
#define OFFS_BASE  8388609        // offsets output base in d_out

// ---------------- ws layout (bytes) ----------------
#define XT_OFF     0u              // fp16 [B][HW][512]       33,554,432
#define HEAD_OFF   33554432u       // head fp8 [NROW][KDIM]   33,554,432 (tail)
#define XF8_OFF    67108864u       // fp8 [B][HW][256] F_c     8,388,608
#define WBF_OFF    100663296u      // fp8 [C][KDIM]            262,144
#define ATTN_OFF   101187584u      // f32 [B][M][HW]           524,288
#define ALPHA_OFF  101711872u      // f32 [8]
#define LOSSP_OFF  101712128u      // f32 [256]
#define WREP_OFF   101714176u      // fp16 wconv blob          221,184 (8 x 1728 granules x 16B)
#define ZPAGE_OFF  101935360u      // 256 B zeros

typedef unsigned short u16;
typedef unsigned char u8;
typedef __attribute__((ext_vector_type(8))) _Float16 f16x8;
typedef __attribute__((ext_vector_type(8))) unsigned short u16x8;
typedef __attribute__((ext_vector_type(4))) float f32x4;
typedef __attribute__((ext_vector_type(2))) float f32x2;

#define GLL(gsrc, ldst) __builtin_amdgcn_global_load_lds( \
    (const __attribute__((address_space(1))) unsigned int*)(gsrc), \
    (__attribute__((address_space(3))) unsigned int*)(ldst), 16, 0, 0)

static __device__ __forceinline__ u16 f2h(float f) {
    __half h = __float2half(f);
    return *(u16*)&h;
}
static __device__ __forceinline__ float h2f(u16 u) {
    __half h = *(__half*)&u;
    return __half2float(h);
}
static __device__ __forceinline__ unsigned int pk4_fp8(float a, float b, float c, float d) {
    int r = __builtin_amdgcn_cvt_pk_fp8_f32(a, b, 0, false);
    r = __builtin_amdgcn_cvt_pk_fp8_f32(c, d, r, true);
    return (unsigned int)r;
}

// ---------------- kernel 1: pack X (fp16 + fp8 F_c) AND prep blobs ----------------
// blocks 0..2047: pack (b 8) x (chtile 4 x 128ch) x (postile 64 x 64pos).
// blocks 2048..2303: wfuse fp8; 2304..2311: wconv fp16 blob; 2312: zpage
__global__ __launch_bounds__(256) void pack_x(
    const float* __restrict__ Fx, const float* __restrict__ Fc,
    u16* __restrict__ Xt, u8* __restrict__ Xf8,
    const float* __restrict__ wf, u8* __restrict__ wf8,
    const float* __restrict__ w_off, const float* __restrict__ w_attn,
    u16* __restrict__ wconv, float* __restrict__ zpage) {
    const int tid = threadIdx.x;
    if (blockIdx.x < 2048) {
        const int blk = blockIdx.x;
        const int b = blk >> 8;
        const int rem = blk & 255;
        const int ch0 = (rem >> 6) << 7;           // 0,128,256,384
        const int pos0 = (rem & 63) << 6;          // 64-position tile
        const int cs = (tid & 15) << 3;            // 8-ch sub-block: 0..120
        const int p4 = (tid >> 4) << 2;            // 0..60
        const float* basep = (ch0 < 256)
            ? Fx + (((size_t)b << 8) + ch0) * HWc
            : Fc + (((size_t)b << 8) + (ch0 - 256)) * HWc;
        float4 v[8];
#pragma unroll
        for (int k = 0; k < 8; ++k)
            v[k] = *(const float4*)(basep + (size_t)(cs + k) * HWc + pos0 + p4);
#pragma unroll
        for (int j = 0; j < 4; ++j) {
            float w[8];
#pragma unroll
            for (int k = 0; k < 8; ++k) w[k] = ((const float*)&v[k])[j];
            u16x8 hi8;
#pragma unroll
            for (int k = 0; k < 8; ++k) hi8[k] = f2h(w[k]);
            const size_t row = ((size_t)b << 12) + pos0 + p4 + j;
            *(u16x8*)(Xt + row * 512 + ch0 + cs) = hi8;
            if (ch0 >= 256) {
                uint2 f8;
                f8.x = pk4_fp8(w[0], w[1], w[2], w[3]);
                f8.y = pk4_fp8(w[4], w[5], w[6], w[7]);
                *(uint2*)(Xf8 + row * 256 + (ch0 - 256) + cs) = f8;
            }
        }
    } else if (blockIdx.x < 2304) {
        const int i = (blockIdx.x - 2048) * 256 + tid;
        const float4 v = *(const float4*)(wf + (size_t)i * 4);
        *(unsigned int*)(wf8 + (size_t)i * 4) = pk4_fp8(v.x, v.y, v.z, v.w);
    } else if (blockIdx.x < 2312) {
        const int step = blockIdx.x - 2304;
        for (int n = tid; n < 1728; n += 256) {   // fp16 blob (hi + lo*512 planes)
            const int par = n & 1;
            const int slot = (n >> 1) & 3;
            const int pair = (n >> 3) % 6;
            const int tap = (n / 48) % 9;
            const int prec = (n / 432) & 1;
            const int sub = n / 864;
            const int oc = pair * 2 + par;
            const int c = slot ^ (pair & 3);
            const int ch = step * 64 + sub * 32 + c * 8;
            u16x8 out;
#pragma unroll
            for (int j = 0; j < 8; ++j) {
                const float v = (oc < 8)
                    ? w_off[((size_t)oc * 512 + ch + j) * 9 + tap]
                    : w_attn[((size_t)(oc - 8) * 512 + ch + j) * 9 + tap];
                const u16 h = f2h(v);
                out[j] = prec ? f2h((v - h2f(h)) * 512.f) : h;
            }
            *(u16x8*)(wconv + ((size_t)step * 1728 + n) * 8) = out;
        }
    } else {
        if (tid < 64) zpage[tid] = 0.f;
    }
}

// ---------------- kernel 2: conv as fp16 MFMA implicit GEMM (hi + scaled-lo W) ----------------
// LDS: X fp16 [buf2][row4][pos66][chunk8]x16B (row 8448, buf 33792)          0..67584
//      B fp16 [sub2][prec2][tap9][pair6][slot4][par2]x16B              67584..95232
#define B_BASE 67584
__global__ __launch_bounds__(512) void conv_mfma(
    const u16* __restrict__ Xt,
    const u16* __restrict__ wconv, const float* __restrict__ zpage,
    const float* __restrict__ b_off, const float* __restrict__ b_attn,
    float* __restrict__ dout, float* __restrict__ attnb, float* __restrict__ lossp) {
    __shared__ char smem[95232];

    const int tid = threadIdx.x;
    const int wv = tid >> 6, lane = tid & 63;
    const int gp = wv >> 2, qd = wv & 3;
    const int l15 = lane & 15, g = lane >> 4;
    const int b = blockIdx.x >> 5;
    const int h0 = (blockIdx.x & 31) * 2;
    const int wrow = qd >> 1, wcol0 = (qd & 1) * 32;

    // zero halo granules (pos 0 and 65)
    if (tid < 128) {
        const float4 z = {0.f, 0.f, 0.f, 0.f};
        const int bu = tid >> 6, rr = (tid >> 4) & 3, hp = (tid >> 3) & 1, cc = tid & 7;
        *(float4*)(smem + bu * 33792 + rr * 8448 + (hp ? 65 : 0) * 128 + cc * 16) = z;
    }

    int pre[2][3];
#pragma unroll
    for (int f = 0; f < 2; ++f)
#pragma unroll
        for (int dx = 0; dx < 3; ++dx) {
            const int p = wcol0 + f * 16 + l15 + dx;      // 0..65
            pre[f][dx] = wrow * 8448 + p * 128 + ((((gp << 2) | g) ^ (p & 7)) << 4);
        }
    const int bpair = l15 >> 1, bpar = l15 & 1;
    const int vb = B_BASE + gp * 13824 + bpair * 128 + ((g ^ (bpair & 3)) << 5) + bpar * 16;

    auto stage_X = [&](int step, int buf) {
#pragma unroll
        for (int k = 0; k < 5; ++k) {
            const int f = k * 8 + wv;                     // round-robin over 36 granules
            if (f < 36) {
                const int rr = f / 9, i = f % 9;
                const int p = i * 8 + (lane >> 3);
                const int c = (lane & 7) ^ (p & 7);
                const int h = h0 - 1 + rr;
                const bool act = (p >= 1) && (p <= 64);
                const char* gsrc = (h >= 0 && h < 64)
                    ? (const char*)(Xt + (((size_t)((b << 12) + h * 64 + p - 1)) << 9) + step * 64 + c * 8)
                    : (const char*)zpage + ((lane & 7) << 4);
                char* ldst = smem + buf * 33792 + rr * 8448 + i * 1024;
                if (act) GLL(gsrc, ldst);
            }
        }
    };
    auto stage_B = [&](int step) {
        for (int i = wv; i < 27; i += 8) {
            const char* gsrc = (const char*)wconv + (((size_t)step * 1728) + i * 64 + lane) * 16;
            GLL(gsrc, smem + B_BASE + i * 1024);
        }
    };

    __syncthreads();                 // halo zeros visible
    stage_X(0, 0);
    stage_B(0);
    __syncthreads();                 // full drain

    f32x4 acc0 = {}, acc1 = {}, aL0 = {}, aL1 = {};

    for (int step = 0; step < 8; ++step) {
        if (step < 7) {
            stage_X(step + 1, (step + 1) & 1);
            // drain prev X + prev B; keep own new X batch (5 for waves 0-3, 4 for 4-7) in flight
            if (wv < 4) asm volatile("s_waitcnt vmcnt(5)" ::: "memory");
            else        asm volatile("s_waitcnt vmcnt(4)" ::: "memory");
        } else {
            asm volatile("s_waitcnt vmcnt(0)" ::: "memory");
        }
        __builtin_amdgcn_s_barrier();
        __builtin_amdgcn_sched_barrier(0);

#pragma unroll
        for (int tap = 0; tap < 9; ++tap) {
            const int dy = tap / 3, dx = tap % 3;
            const f16x8 bh = *(const f16x8*)(smem + vb + tap * 768);
            const f16x8 bl = *(const f16x8*)(smem + vb + 6912 + tap * 768);
            const f16x8 a0 = *(const f16x8*)(smem + pre[0][dx] + dy * 8448);
            const f16x8 a1 = *(const f16x8*)(smem + pre[1][dx] + dy * 8448);
            acc0 = __builtin_amdgcn_mfma_f32_16x16x32_f16(a0, bh, acc0, 0, 0, 0);
            acc1 = __builtin_amdgcn_mfma_f32_16x16x32_f16(a1, bh, acc1, 0, 0, 0);
            aL0  = __builtin_amdgcn_mfma_f32_16x16x32_f16(a0, bl, aL0, 0, 0, 0);
            aL1  = __builtin_amdgcn_mfma_f32_16x16x32_f16(a1, bl, aL1, 0, 0, 0);
        }

        __builtin_amdgcn_sched_barrier(0);
        __builtin_amdgcn_s_barrier();
        __builtin_amdgcn_sched_barrier(0);
        if (step < 7) stage_B(step + 1);
        const int dh = (step & 1) ? -33792 : 33792;
#pragma unroll
        for (int f = 0; f < 2; ++f)
#pragma unroll
            for (int dx = 0; dx < 3; ++dx) pre[f][dx] += dh;
    }

    // ---- epilogue ----
    __syncthreads();
    float* eL = (float*)smem;        // [2 groups][12 oc][128 pix]
    if (l15 < 12) {
#pragma unroll
        for (int r = 0; r < 4; ++r) {
            const int px0 = wrow * 64 + wcol0 + g * 4 + r;
            eL[(gp * 12 + l15) * 128 + px0] = acc0[r] + aL0[r] * (1.f / 512.f);
            eL[(gp * 12 + l15) * 128 + px0 + 16] = acc1[r] + aL1[r] * (1.f / 512.f);
        }
    }
    __syncthreads();
    float labs = 0.f;
    if (tid < 256) {
        const int oc = tid >> 5, seg = tid & 31;
        const float4 v0 = *(const float4*)&eL[oc * 128 + seg * 4];
        const float4 v1 = *(const float4*)&eL[(12 + oc) * 128 + seg * 4];
        const float bo = b_off[oc];
        float4 o;
        o.x = v0.x + v1.x + bo; o.y = v0.y + v1.y + bo;
        o.z = v0.z + v1.z + bo; o.w = v0.w + v1.w + bo;
        *(float4*)(dout + OFFS_BASE + (((size_t)b * 8 + oc) << 12) + h0 * 64 + seg * 4) = o;
        labs = fabsf(o.x) + fabsf(o.y) + fabsf(o.z) + fabsf(o.w);
    } else if (tid < 384) {
        const int t2 = tid - 256;
        const int oc = t2 >> 5, seg = t2 & 31;
        const float4 v0 = *(const float4*)&eL[(8 + oc) * 128 + seg * 4];
        const float4 v1 = *(const float4*)&eL[(20 + oc) * 128 + seg * 4];
        const float ba = b_attn[oc];
        float4 o;
        o.x = 1.f / (1.f + expf(-(v0.x + v1.x + ba)));
        o.y = 1.f / (1.f + expf(-(v0.y + v1.y + ba)));
        o.z = 1.f / (1.f + expf(-(v0.z + v1.z + ba)));
        o.w = 1.f / (1.f + expf(-(v0.w + v1.w + ba)));
        *(float4*)(attnb + (((size_t)b * 4 + oc) << 12) + h0 * 64 + seg * 4) = o;
    }
#pragma unroll
    for (int off = 32; off; off >>= 1) labs += __shfl_down(labs, off);
    float* wr = (float*)(smem + 14336);
    if (lane == 0) wr[wv] = labs;
    __syncthreads();
    if (tid == 0) {
        float s = 0.f;
#pragma unroll
        for (int i = 0; i < 8; ++i) s += wr[i];
        lossp[blockIdx.x] = s;
    }
}

// ---------------- kernel 3: loss reduce + alpha MLP ----------------
__global__ __launch_bounds__(256) void finalize_small(
    const float* __restrict__ lossp, const float* __restrict__ t,
    const float* __restrict__ w1, const float* __restrict__ b1,
    const float* __restrict__ w2, const float* __restrict__ b2,
    float* __restrict__ dout, float* __restrict__ alpha) {
    __shared__ float sd[4];
    const int tid = threadIdx.x;
    float s = lossp[tid];
#pragma unroll
    for (int off = 32; off; off >>= 1) s += __shfl_down(s, off);
    if ((tid & 63) == 0) sd[tid >> 6] = s;
    __syncthreads();
    if (tid == 0) dout[LOSS_IDX] = (sd[0] + sd[1] + sd[2] + sd[3]) * (1.f / 262144.f);

    for (int b = 0; b < 8; ++b) {
        __syncthreads();
        float v = 0.f;
        if (tid < 128) v = fmaxf(fmaf(t[b], w1[tid], b1[tid]), 0.f) * w2[tid];
#pragma unroll
        for (int off = 32; off; off >>= 1) v += __shfl_down(v, off);
        if ((tid & 63) == 0) sd[tid >> 6] = v;
        __syncthreads();
        if (tid == 0) alpha[b] = 1.f / (1.f + expf(-(sd[0] + sd[1] + b2[0])));
    }
}

// ---------------- kernel 4: bilinear gather (fp8) -> head (fp8) ----------------
__global__ __launch_bounds__(256) void sample_head(
    const u8* __restrict__ Xf8, const float* __restrict__ dout,
    const float* __restrict__ attnb, const float* __restrict__ Wp,
    u8* __restrict__ head) {
    const int tid = threadIdx.x;
    const int wv = tid >> 6, lane = tid & 63;
    const int item = blockIdx.x * 4 + wv;           // (b, m, p)
    const int b = item >> 14;
    const int m = (item >> 12) & 3;
    const int p = item & 4095;
    const int h = p >> 6, wc = p & 63;
    const int hl = lane >> 5, l32 = lane & 31;

    const float off0 = dout[OFFS_BASE + (((size_t)b * 8 + 2 * m) << 12) + p];
    const float off1 = dout[OFFS_BASE + (((size_t)b * 8 + 2 * m + 1) << 12) + p];
    const float a    = attnb[(((size_t)b * 4 + m) << 12) + p];

    const float ysh = -1.f + h * (2.f / 63.f);
    const float xsw = -1.f + wc * (2.f / 63.f);

    const u8* base = Xf8 + (((size_t)b << 12) << 8) + l32 * 8;
    float acc[8] = {};

#pragma unroll
    for (int r = 0; r < 4; ++r) {
        const float bpy = (r < 2) ? -0.5f : 0.5f;
        const float bpx = (r & 1) ? 0.5f : -0.5f;
        const float c0 = ysh + bpy + off0;   // used as gx (reference quirk)
        const float c1 = xsw + bpx + off1;   // used as gy
        const float ix = (c0 + 1.f) * 31.5f;
        const float iy = (c1 + 1.f) * 31.5f;
        const float x0 = floorf(ix), y0 = floorf(iy);
        const float wx1 = ix - x0, wx0 = 1.f - wx1;
        const float wy1 = iy - y0, wy0 = 1.f - wy1;
        const float xf = x0 + hl;
        const float wxl = (hl ? wx1 : wx0) * (Wp[m * 4 + r] * a);
        const bool xin = (xf >= 0.f) && (xf < 64.f);
        const bool v0 = xin && (y0 >= 0.f) && (y0 < 64.f);
        const bool v1 = xin && (y0 >= -1.f) && (y0 < 63.f);
        const int xi = (int)xf;
        uint2 u0, u1;
        if (v0) u0 = *(const uint2*)(base + ((size_t)((((int)y0) << 6) + xi)) * 256);
        if (v1) u1 = *(const uint2*)(base + ((size_t)((((int)y0 + 1) << 6) + xi)) * 256);
        if (v0) {
            const float w = wxl * wy0;
            const f32x2 pa = __builtin_amdgcn_cvt_pk_f32_fp8((int)u0.x, false);
            const f32x2 pb = __builtin_amdgcn_cvt_pk_f32_fp8((int)u0.x, true);
            const f32x2 pc = __builtin_amdgcn_cvt_pk_f32_fp8((int)u0.y, false);
            const f32x2 pd = __builtin_amdgcn_cvt_pk_f32_fp8((int)u0.y, true);
            acc[0] = fmaf(w, pa[0], acc[0]); acc[1] = fmaf(w, pa[1], acc[1]);
            acc[2] = fmaf(w, pb[0], acc[2]); acc[3] = fmaf(w, pb[1], acc[3]);
            acc[4] = fmaf(w, pc[0], acc[4]); acc[5] = fmaf(w, pc[1], acc[5]);
            acc[6] = fmaf(w, pd[0], acc[6]); acc[7] = fmaf(w, pd[1], acc[7]);
        }
        if (v1) {
            const float w = wxl * wy1;
            const f32x2 pa = __builtin_amdgcn_cvt_pk_f32_fp8((int)u1.x, false);
            const f32x2 pb = __builtin_amdgcn_cvt_pk_f32_fp8((int)u1.x, true);
            const f32x2 pc = __builtin_amdgcn_cvt_pk_f32_fp8((int)u1.y, false);
            const f32x2 pd = __builtin_amdgcn_cvt_pk_f32_fp8((int)u1.y, true);
            acc[0] = fmaf(w, pa[0], acc[0]); acc[1] = fmaf(w, pa[1], acc[1]);
            acc[2] = fmaf(w, pb[0], acc[2]); acc[3] = fmaf(w, pb[1], acc[3]);
            acc[4] = fmaf(w, pc[0], acc[4]); acc[5] = fmaf(w, pc[1], acc[5]);
            acc[6] = fmaf(w, pd[0], acc[6]); acc[7] = fmaf(w, pd[1], acc[7]);
        }
    }
#pragma unroll
    for (int j = 0; j < 8; ++j) acc[j] += __shfl_xor(acc[j], 32);
    if (lane < 32) {
        uint2 o;
        o.x = pk4_fp8(acc[0], acc[1], acc[2], acc[3]);
        o.y = pk4_fp8(acc[4], acc[5], acc[6], acc[7]);
        *(uint2*)(head + ((((size_t)b << 12) + p)) * KDIM + m * 256 + l32 * 8) = o;
    }
}

// ---------------- kernel 5: fuse GEMM (fp8 MFMA, K-tile 64, swizzled global_load_lds) ----------------
__global__ __launch_bounds__(256) void fuse_gemm(
    const u8* __restrict__ head, const u8* __restrict__ wf8,
    const float* __restrict__ Fx, const float* __restrict__ bfuse,
    const float* __restrict__ alpha, float* __restrict__ dout) {
    __shared__ __attribute__((aligned(16))) char smem[2][2][8192];   // [buf][A/B][128*64]

    const int tid = threadIdx.x;
    const int lane = tid & 63, wv = tid >> 6;
    const int wm = wv >> 1, wn = wv & 1;
    const int l15 = lane & 15, g = lane >> 4;
    const size_t arow0 = (size_t)blockIdx.x * 128;
    const int co0 = blockIdx.y * 128;

    f32x4 acc[4][4] = {};

    const int isB = wv >> 1;
    const int whalf = wv & 1;
    const u8* srcbase = isB ? wf8 + (size_t)co0 * KDIM : head + arow0 * KDIM;

    auto stage = [&](int kt, int buf) {
#pragma unroll
        for (int i = 0; i < 4; ++i) {
            const int row = whalf * 64 + i * 16 + (lane >> 2);
            const int gq = (lane & 3) ^ ((row >> 1) & 3);
            const u8* gsrc = srcbase + (size_t)row * KDIM + kt * 64 + gq * 16;
            char* ldst = smem[buf][isB] + (whalf * 64 + i * 16) * 64;
            GLL(gsrc, ldst);
        }
    };

    stage(0, 0);
    __syncthreads();

    for (int kt = 0; kt < 16; ++kt) {
        if (kt < 15) {
            stage(kt + 1, (kt + 1) & 1);
            asm volatile("s_waitcnt vmcnt(4)" ::: "memory");
        } else {
            asm volatile("s_waitcnt vmcnt(0)" ::: "memory");
        }
        __builtin_amdgcn_s_barrier();
        __builtin_amdgcn_sched_barrier(0);

        const char* Ab = smem[kt & 1][0];
        const char* Bb = smem[kt & 1][1];
#pragma unroll
        for (int s = 0; s < 2; ++s) {
            const int gg = s * 4 + g;
            long av[4], bv[4];
#pragma unroll
            for (int f = 0; f < 4; ++f) {
                const int ra = wm * 64 + f * 16 + l15;
                const int rb = wn * 64 + f * 16 + l15;
                const int sa = (gg >> 1) ^ ((ra >> 1) & 3);
                const int sb = (gg >> 1) ^ ((rb >> 1) & 3);
                av[f] = *(const long*)(Ab + ra * 64 + sa * 16 + (gg & 1) * 8);
                bv[f] = *(const long*)(Bb + rb * 64 + sb * 16 + (gg & 1) * 8);
            }
#pragma unroll
            for (int i = 0; i < 4; ++i)
#pragma unroll
                for (int j = 0; j < 4; ++j)
                    acc[i][j] = __builtin_amdgcn_mfma_f32_16x16x32_fp8_fp8(av[i], bv[j], acc[i][j], 0, 0, 0);
        }

        __builtin_amdgcn_sched_barrier(0);
        __builtin_amdgcn_s_barrier();
        __builtin_amdgcn_sched_barrier(0);
    }

    const int b = (int)(arow0 >> 12);
    const float al = alpha[b], il = 1.f - al;
    const int pixbase = (int)(arow0 & 4095);
#pragma unroll
    for (int i = 0; i < 4; ++i) {
        const int rowl = wm * 64 + i * 16 + g * 4;
        const int pix = pixbase + rowl;
#pragma unroll
        for (int j = 0; j < 4; ++j) {
            const int co = co0 + wn * 64 + j * 16 + l15;
            const float bias = bfuse[co];
            const size_t idx = (((size_t)b << 8) + co) * HWc + pix;
            const float4 fx = *(const float4*)(Fx + idx);
            const f32x4 v = acc[i][j];
            float4 o;
            o.x = al * (v[0] + bias) + il * fx.x;
            o.y = al * (v[1] + bias) + il * fx.y;
            o.z = al * (v[2] + bias) + il * fx.z;
            o.w = al * (v[3] + bias) + il * fx.w;
            *(float4*)(dout + idx) = o;
        }
    }
}

// ---------------- launcher ----------------
extern "C" void kernel_launch(void* const* d_in, const int* in_sizes, int n_in,
                              void* d_out, int out_size, void* d_ws, size_t ws_size,
                              hipStream_t stream) {
    const float* F_x    = (const float*)d_in[0];
    const float* F_c    = (const float*)d_in[1];
    const float* t      = (const float*)d_in[2];
    const float* w_off  = (const float*)d_in[3];
    const float* b_off  = (const float*)d_in[4];
    const float* w_attn = (const float*)d_in[5];
    const float* b_attn = (const float*)d_in[6];
    const float* Wp     = (const float*)d_in[7];
    const float* w_fuse = (const float*)d_in[8];
    const float* b_fuse = (const float*)d_in[9];
    const float* w1     = (const float*)d_in[10];
    const float* b1     = (const float*)d_in[11];
    const float* w2     = (const float*)d_in[12];
    const float* b2     = (const float*)d_in[13];
    float* out = (float*)d_out;

    char* ws = (char*)d_ws;
    u16*   Xt     = (u16*)(ws + XT_OFF);
    u8*    head8  = (u8*)(ws + HEAD_OFF);     // fp8 head, 32 MB
    u8*    Xf8    = (u8*)(ws + XF8_OFF);
    u8*    wf8    = (u8*)(ws + WBF_OFF);
    float* attnb  = (float*)(ws + ATTN_OFF);
    float* alphb  = (float*)(ws + ALPHA_OFF);
    float* lossp  = (float*)(ws + LOSSP_OFF);
    u16*   wconv  = (u16*)(ws + WREP_OFF);
    float* zpage  = (float*)(ws + ZPAGE_OFF);

    pack_x<<<dim3(2313), dim3(256), 0, stream>>>(F_x, F_c, Xt, Xf8,
                                                 w_fuse, wf8, w_off, w_attn,
                                                 wconv, zpage);
    conv_mfma<<<dim3(256), dim3(512), 0, stream>>>(Xt, wconv, zpage,
                                                   b_off, b_attn, out, attnb, lossp);
    finalize_small<<<dim3(1), dim3(256), 0, stream>>>(lossp, t, w1, b1, w2, b2, out, alphb);
    sample_head<<<dim3(32768), dim3(256), 0, stream>>>(Xf8, out, attnb, Wp, head8);
    fuse_gemm<<<dim3(256, 2), dim3(256), 0, stream>>>(head8, wf8, F_x, b_fuse, alphb, out);
}